// Round 13
// baseline (51.888 us; speedup 1.0000x reference)
//
#include <hip/hip_runtime.h>
#include <hip/hip_bf16.h>
#include <stdint.h>

#define BB    8
#define NN    4096
#define FIN   32
#define FF    33         // FIN + 1 noise channel
#define KPAD  64         // feature dim padded; dims 33,34 carry the threshold fold
#define NQ    (BB*NN)    // 32768 query points
#define CAP   32
#define NTRI  136        // 16*17/2 slab pairs (qt <= ms), 256-row q-slabs
#define INF_IDX 0x7FFFFFFF

// Sieve: d2 < 14 (dropped survivors weigh <= e^-14; r8 confirmed absmax 9.8e-4).
// Augmentation: fbA[33]=3.5-sq/2, fbA[34]=1 ; fbB[33]=1, fbB[34]=3.5-sq/2
// => acc = dot - 0.5*sq_n - 0.5*sq_m + 7 ; acc > 0 <=> d2 < 14
//
// r11 post-mortem: knn FETCH=29MB vs 8MB inputs — blocks round-robin across
// 8 XCDs so each private L2 re-fetches the whole working set from HBM, and
// every B-load pays ~900cy HBM-miss instead of ~200cy L2-hit. This round:
// XCD-pin by batch (blockIdx%8 == bb; BB==NXCD==8, 1MB/batch << 4MB L2).

// ---- lists path: ~12.4 MB ----
#define OFF_FBA    0ull
#define OFF_FBB    (OFF_FBA   + (size_t)NQ*KPAD*2)    // +4 MB
#define OFF_CNT    (OFF_FBB   + (size_t)NQ*KPAD*2)    // +4 MB
#define OFF_LISTS  (OFF_CNT   + (size_t)NQ*4)         // +128 KB
#define OFF_PART   (OFF_LISTS + (size_t)NQ*CAP*4)     // +4 MB
#define WS_NEED    (OFF_PART  + (size_t)(NQ/8)*4)

typedef short short8 __attribute__((ext_vector_type(8)));
typedef float floatx4 __attribute__((ext_vector_type(4)));

// ---------------- prep: f=[x,noise] -> two augmented bf16 arrays; zero cnt ----------------
// XCD-pinned: bb = blockIdx & 7
__global__ __launch_bounds__(64) void prep_kernel(const float* __restrict__ x,
                                                  const float* __restrict__ noise,
                                                  unsigned short* __restrict__ fbA,
                                                  unsigned short* __restrict__ fbB,
                                                  int* __restrict__ cnt) {
    int bb = blockIdx.x & 7;
    int j  = blockIdx.x >> 3;            // 0..63 within batch
    int q  = bb * NN + j * 64 + threadIdx.x;
    cnt[q] = 0;
    const float4* xr = (const float4*)(x + (size_t)q * FIN);
    float v[FF];
#pragma unroll
    for (int i = 0; i < 8; ++i) {
        float4 t = xr[i];
        v[i*4+0] = t.x; v[i*4+1] = t.y; v[i*4+2] = t.z; v[i*4+3] = t.w;
    }
    v[32] = noise[q];
    float s = 0.f;
#pragma unroll
    for (int d = 0; d < FF; ++d) s += v[d] * v[d];
    unsigned short rowA[KPAD], rowB[KPAD];
#pragma unroll
    for (int d = 0; d < FF; ++d) {
        __hip_bfloat16 h = __float2bfloat16(v[d]);
        unsigned short u = *(unsigned short*)&h;
        rowA[d] = u; rowB[d] = u;
    }
    __hip_bfloat16 hs = __float2bfloat16(3.5f - 0.5f * s);   // THR/4 - sq/2
    unsigned short us = *(unsigned short*)&hs;
    const unsigned short one = 0x3F80;   // bf16 1.0
    rowA[33] = us;  rowA[34] = one;
    rowB[33] = one; rowB[34] = us;
#pragma unroll
    for (int d = 35; d < KPAD; ++d) { rowA[d] = 0; rowB[d] = 0; }
    uint4* dA = (uint4*)(fbA + (size_t)q * KPAD);
    uint4* dB = (uint4*)(fbB + (size_t)q * KPAD);
#pragma unroll
    for (int i = 0; i < 8; ++i) { dA[i] = ((const uint4*)rowA)[i]; dB[i] = ((const uint4*)rowB)[i]; }
}

// ---------------- phase 1: symmetric MFMA sieve, all-8-B-tile preload, XCD-pinned ----------------
// blockIdx = (pair index)*8 + bb  =>  batch bb runs on XCD bb; its 1 MB working
// set stays L2-resident. Triangle (qt<=ms, msub): q-slab 256 (wave = 4 A-tiles),
// m-range 128 (8 tiles, ALL preloaded).
__global__ __launch_bounds__(256) void knn_kernel(const unsigned short* __restrict__ fbA,
                                                  const unsigned short* __restrict__ fbB,
                                                  int* __restrict__ cnt,
                                                  int* __restrict__ lists) {
    int bb  = blockIdx.x & 7;
    int rem = blockIdx.x >> 3;           // 0..271 pair index
    int tri = rem >> 1, msub = rem & 1;
    int t = tri, qt = 0;
    while (t >= 16 - qt) { t -= 16 - qt; ++qt; }
    int ms = qt + t;

    int wid = threadIdx.x >> 6, lane = threadIdx.x & 63;
    int qb  = qt * 256 + wid * 64;       // wave's query base (batch-local)
    int mstart = ms * 256 + msub * 128;
    if (mstart + 128 <= qb) return;      // wave entirely below diagonal: no work

    int g16 = lane >> 4, l16 = lane & 15;
    size_t base = (size_t)bb * NN;

    // A fragments: 4 tiles of 16 q-rows (32 VGPR)
    short8 a0[4], a1[4];
#pragma unroll
    for (int a = 0; a < 4; ++a) {
        const short8* pA = (const short8*)fbA + ((base + qb + a * 16 + l16) * 8 + g16);
        a0[a] = pA[0];
        a1[a] = pA[4];   // k += 32
    }

    // B fragments: ALL 8 m-tiles preloaded (64 VGPR, 16 independent loads in flight)
    const short8* pB = (const short8*)fbB + ((base + mstart + l16) * 8 + g16);
    short8 b0[8], b1[8];
#pragma unroll
    for (int mt = 0; mt < 8; ++mt) {
        b0[mt] = pB[mt * 128];
        b1[mt] = pB[mt * 128 + 4];
    }

#pragma unroll
    for (int mt = 0; mt < 8; ++mt) {
        int mb = mstart + mt * 16;
        if (mb + 16 > qb) {              // skip tiles fully below the wave's diagonal
            int m = mb + l16;
#pragma unroll
            for (int a = 0; a < 4; ++a) {
                floatx4 acc = {0.f, 0.f, 0.f, 0.f};
                acc = __builtin_amdgcn_mfma_f32_16x16x32_bf16(a0[a], b0[mt], acc, 0, 0, 0);
                acc = __builtin_amdgcn_mfma_f32_16x16x32_bf16(a1[a], b1[mt], acc, 0, 0, 0);
                float mm = fmaxf(fmaxf(acc[0], acc[1]), fmaxf(acc[2], acc[3]));
                if (mm > 0.f) {
#pragma unroll
                    for (int r = 0; r < 4; ++r) {
                        int n = qb + a * 16 + g16 * 4 + r;   // C/D row = (lane>>4)*4 + reg
                        if (acc[r] > 0.f && m > n) {
                            int p1 = atomicAdd(&cnt[base + n], 1);
                            if (p1 < CAP) lists[(base + n) * CAP + p1] = m;
                            int p2 = atomicAdd(&cnt[base + m], 1);
                            if (p2 < CAP) lists[(base + m) * CAP + p2] = n;
                        }
                    }
                }
            }
        }
    }
}

// ---------------- phase 2: 2 queries per wave; exact fp32 weights; fused head ----------------
// XCD-pinned: bb = blockIdx & 7, j = blockIdx>>3 (0..511), block owns 8 queries.
// Lanes 0-31 = query q0 (d=hl), lanes 32-63 = q1. d=32 (noise) folded onto hl==0.
__global__ __launch_bounds__(256) void gather_kernel(const float* __restrict__ x,
                                                     const float* __restrict__ noise,
                                                     const float* __restrict__ y,
                                                     const float* __restrict__ W1,
                                                     const float* __restrict__ b1,
                                                     const int* __restrict__ cnt,
                                                     const int* __restrict__ lists,
                                                     float* __restrict__ out,
                                                     float* __restrict__ partials) {
    __shared__ float e_lds[8][2 * FF];
    __shared__ float msep[8];
    int bb = blockIdx.x & 7;
    int j  = blockIdx.x >> 3;
    int q0blk = bb * NN + j * 8;
    int wid = threadIdx.x >> 6, lane = threadIdx.x & 63;
    int hf = lane >> 5, hl = lane & 31;           // half index, lane-in-half
    int q  = q0blk + wid * 2 + hf;
    size_t base = (size_t)bb * NN;

    float fnd  = x[(size_t)q * FIN + hl];
    float fnd2 = (hl == 0) ? noise[q] : 0.f;      // d=32 slot

    int c = cnt[q];
    if (c > CAP) c = CAP;
    int mj = (hl < c) ? lists[(size_t)q * CAP + hl] : INF_IDX;

    float den = 1.f, num = 0.f, num2 = 0.f;       // self: w=1, diff=0
    for (;;) {
        int v = mj;                               // per-half min (xor<=16 stays in half)
#pragma unroll
        for (int off = 16; off; off >>= 1) {
            int o = __shfl_xor(v, off);
            v = v < o ? v : o;
        }
        if (__ballot(v != INF_IDX) == 0ull) break;   // both halves exhausted
        bool act = (v != INF_IDX);
        if (mj == v) mj = INF_IDX;
        int m = act ? v : 0;
        float fm  = x[(base + m) * (size_t)FIN + hl];
        float fm2 = (hl == 0) ? noise[base + m] : 0.f;
        float diff  = fm - fnd;
        float diff2 = fm2 - fnd2;
        float s = diff * diff + diff2 * diff2;
#pragma unroll
        for (int off = 16; off; off >>= 1) s += __shfl_xor(s, off);
        float wgt = act ? __expf(-s) : 0.f;       // exact fp32 d2
        den += wgt;
        num += wgt * diff;
        num2 += wgt * diff2;
    }
    float md = num / den, md2 = num2 / den;       // den >= 1 always

    int qs = wid * 2 + hf;                        // 0..7 query slot in block
    e_lds[qs][hl]      = fnd;
    e_lds[qs][FF + hl] = md;
    if (hl == 0) { e_lds[qs][32] = fnd2; e_lds[qs][FF + 32] = md2; }
    __syncthreads();

    // head: thread = (query hq, channel ch); 8 x 32 = 256
    int hq = threadIdx.x >> 5, ch = threadIdx.x & 31;
    int qq = q0blk + hq;
    float g0 = b1[ch], g1 = 0.f;                  // split dependent chain
#pragma unroll
    for (int e = 0; e < 2 * FF; e += 2) {
        g0 = fmaf(e_lds[hq][e],     W1[e * FIN + ch],       g0);
        g1 = fmaf(e_lds[hq][e + 1], W1[(e + 1) * FIN + ch], g1);
    }
    float g = fmaxf(g0 + g1, 0.f);
    out[(size_t)qq * FIN + ch] = g;
    float tt = g - y[(size_t)qq * FIN + ch];
    float d = tt * tt;
#pragma unroll
    for (int off = 16; off; off >>= 1) d += __shfl_xor(d, off);
    if (ch == 0) msep[hq] = d;
    __syncthreads();
    if (threadIdx.x == 0) {
        float a = 0.f;
#pragma unroll
        for (int i = 0; i < 8; ++i) a += msep[i];
        partials[blockIdx.x] = a;
    }
}

// ---------------- phase 2 (brute, ws-too-small last resort) ----------------
__global__ __launch_bounds__(256) void gather_brute(const float* __restrict__ x,
                                                    const float* __restrict__ noise,
                                                    const float* __restrict__ y,
                                                    const float* __restrict__ W1,
                                                    const float* __restrict__ b1,
                                                    float* __restrict__ out,
                                                    float* __restrict__ partials) {
    __shared__ float e_lds[4][2 * FF];
    __shared__ float msep[4];
    int wid = threadIdx.x >> 6, lane = threadIdx.x & 63;
    int q = blockIdx.x * 4 + wid;
    int bb = q >> 12;
    int nloc = q & (NN - 1);
    size_t base = (size_t)bb * NN;

    float fnd = 0.f;
    if (lane < FIN)          fnd = x[(size_t)q * FIN + lane];
    else if (lane == FF - 1) fnd = noise[q];

    float den = 1.f, num = 0.f;
    for (int m = 0; m < NN; ++m) {
        if (m == nloc) continue;
        float fmd = 0.f;
        if (lane < FIN)          fmd = x[(base + m) * (size_t)FIN + lane];
        else if (lane == FF - 1) fmd = noise[base + m];
        float diff = (lane < FF) ? (fmd - fnd) : 0.f;
        float s = diff * diff;
#pragma unroll
        for (int off = 32; off; off >>= 1) s += __shfl_xor(s, off);
        float w = __expf(-s);
        den += w;
        num += w * diff;
    }
    float md = num / den;

    if (lane < FF) { e_lds[wid][lane] = fnd; e_lds[wid][FF + lane] = md; }
    __syncthreads();
    float g = 0.f;
    if (lane < FIN) {
        g = b1[lane];
#pragma unroll
        for (int e = 0; e < 2 * FF; ++e)
            g = fmaf(e_lds[wid][e], W1[e * FIN + lane], g);
        g = fmaxf(g, 0.f);
        out[(size_t)q * FIN + lane] = g;
    }
    float d = 0.f;
    if (lane < FIN) {
        float t = g - y[(size_t)q * FIN + lane];
        d = t * t;
    }
#pragma unroll
    for (int off = 32; off; off >>= 1) d += __shfl_xor(d, off);
    if (lane == 0) msep[wid] = d;
    __syncthreads();
    if (threadIdx.x == 0)
        partials[blockIdx.x] = msep[0] + msep[1] + msep[2] + msep[3];
}

// ---------------- final: gen_mse (n4 = partial count / 4) ----------------
__global__ __launch_bounds__(256) void reduce_kernel(const float* __restrict__ partials,
                                                     float* __restrict__ out, int n4) {
    __shared__ float sw[4];
    int wid = threadIdx.x >> 6, lane = threadIdx.x & 63;
    const float4* p4 = (const float4*)partials;
    float ax = 0.f, ay = 0.f, az = 0.f, aw = 0.f;
    for (int i = threadIdx.x; i < n4; i += 256) {
        float4 v = p4[i];
        ax += v.x; ay += v.y; az += v.z; aw += v.w;
    }
    float a = (ax + ay) + (az + aw);
#pragma unroll
    for (int off = 32; off; off >>= 1) a += __shfl_xor(a, off);
    if (lane == 0) sw[wid] = a;
    __syncthreads();
    if (threadIdx.x == 0)
        out[(size_t)NQ * FIN] = (sw[0] + sw[1] + sw[2] + sw[3]) / (float)((size_t)NQ * FIN);
}

extern "C" void kernel_launch(void* const* d_in, const int* in_sizes, int n_in,
                              void* d_out, int out_size, void* d_ws, size_t ws_size,
                              hipStream_t stream) {
    const float* x     = (const float*)d_in[0];
    const float* noise = (const float*)d_in[1];
    const float* y     = (const float*)d_in[2];
    const float* W1    = (const float*)d_in[3];
    const float* b1    = (const float*)d_in[4];
    float* out = (float*)d_out;
    char* ws = (char*)d_ws;

    if (ws_size >= WS_NEED) {
        unsigned short* fbA = (unsigned short*)(ws + OFF_FBA);
        unsigned short* fbB = (unsigned short*)(ws + OFF_FBB);
        int*   cnt     = (int*)(ws + OFF_CNT);
        int*   lists   = (int*)(ws + OFF_LISTS);
        float* partial = (float*)(ws + OFF_PART);

        prep_kernel<<<NQ / 64, 64, 0, stream>>>(x, noise, fbA, fbB, cnt);
        knn_kernel<<<BB * NTRI * 2, 256, 0, stream>>>(fbA, fbB, cnt, lists);
        gather_kernel<<<NQ / 8, 256, 0, stream>>>(x, noise, y, W1, b1, cnt, lists, out, partial);
        reduce_kernel<<<1, 256, 0, stream>>>(partial, out, (NQ / 8) / 4);
    } else {
        float* partial = (float*)ws;
        gather_brute<<<NQ / 4, 256, 0, stream>>>(x, noise, y, W1, b1, out, partial);
        reduce_kernel<<<1, 256, 0, stream>>>(partial, out, (NQ / 4) / 4);
    }
}

// Round 14
// 51.711 us; speedup vs baseline: 1.0034x; 1.0034x over previous
//
#include <hip/hip_runtime.h>
#include <hip/hip_bf16.h>
#include <stdint.h>

#define BB    8
#define NN    4096
#define FIN   32
#define FF    33         // FIN + 1 noise channel
#define KPAD  64         // feature dim padded; dims 33,34 carry the threshold fold
#define NQ    (BB*NN)    // 32768 query points
#define CAP   32
#define NTRI  136        // 16*17/2 slab pairs (qt <= ms), 256-row q-slabs
#define INF_IDX 0x7FFFFFFF

// Sieve: d2 < 14 (dropped survivors weigh <= e^-14; r8 confirmed absmax 9.8e-4).
// Augmentation: fbA[33]=3.5-sq/2, fbA[34]=1 ; fbB[33]=1, fbB[34]=3.5-sq/2
// => acc = dot - 0.5*sq_n - 0.5*sq_m + 7 ; acc > 0 <=> d2 < 14
//
// r11 post-mortem: knn FETCH=29MB vs 8MB inputs — blocks round-robin across
// 8 XCDs so each private L2 re-fetches the whole working set from HBM, and
// every B-load pays ~900cy HBM-miss instead of ~200cy L2-hit. This round:
// XCD-pin by batch (blockIdx%8 == bb; BB==NXCD==8, 1MB/batch << 4MB L2).

// ---- lists path: ~12.4 MB ----
#define OFF_FBA    0ull
#define OFF_FBB    (OFF_FBA   + (size_t)NQ*KPAD*2)    // +4 MB
#define OFF_CNT    (OFF_FBB   + (size_t)NQ*KPAD*2)    // +4 MB
#define OFF_LISTS  (OFF_CNT   + (size_t)NQ*4)         // +128 KB
#define OFF_PART   (OFF_LISTS + (size_t)NQ*CAP*4)     // +4 MB
#define WS_NEED    (OFF_PART  + (size_t)(NQ/8)*4)

typedef short short8 __attribute__((ext_vector_type(8)));
typedef float floatx4 __attribute__((ext_vector_type(4)));

// ---------------- prep: f=[x,noise] -> two augmented bf16 arrays; zero cnt ----------------
// XCD-pinned: bb = blockIdx & 7
__global__ __launch_bounds__(64) void prep_kernel(const float* __restrict__ x,
                                                  const float* __restrict__ noise,
                                                  unsigned short* __restrict__ fbA,
                                                  unsigned short* __restrict__ fbB,
                                                  int* __restrict__ cnt) {
    int bb = blockIdx.x & 7;
    int j  = blockIdx.x >> 3;            // 0..63 within batch
    int q  = bb * NN + j * 64 + threadIdx.x;
    cnt[q] = 0;
    const float4* xr = (const float4*)(x + (size_t)q * FIN);
    float v[FF];
#pragma unroll
    for (int i = 0; i < 8; ++i) {
        float4 t = xr[i];
        v[i*4+0] = t.x; v[i*4+1] = t.y; v[i*4+2] = t.z; v[i*4+3] = t.w;
    }
    v[32] = noise[q];
    float s = 0.f;
#pragma unroll
    for (int d = 0; d < FF; ++d) s += v[d] * v[d];
    unsigned short rowA[KPAD], rowB[KPAD];
#pragma unroll
    for (int d = 0; d < FF; ++d) {
        __hip_bfloat16 h = __float2bfloat16(v[d]);
        unsigned short u = *(unsigned short*)&h;
        rowA[d] = u; rowB[d] = u;
    }
    __hip_bfloat16 hs = __float2bfloat16(3.5f - 0.5f * s);   // THR/4 - sq/2
    unsigned short us = *(unsigned short*)&hs;
    const unsigned short one = 0x3F80;   // bf16 1.0
    rowA[33] = us;  rowA[34] = one;
    rowB[33] = one; rowB[34] = us;
#pragma unroll
    for (int d = 35; d < KPAD; ++d) { rowA[d] = 0; rowB[d] = 0; }
    uint4* dA = (uint4*)(fbA + (size_t)q * KPAD);
    uint4* dB = (uint4*)(fbB + (size_t)q * KPAD);
#pragma unroll
    for (int i = 0; i < 8; ++i) { dA[i] = ((const uint4*)rowA)[i]; dB[i] = ((const uint4*)rowB)[i]; }
}

// ---------------- phase 1: symmetric MFMA sieve, all-8-B-tile preload, XCD-pinned ----------------
// blockIdx = (pair index)*8 + bb  =>  batch bb runs on XCD bb; its 1 MB working
// set stays L2-resident. Triangle (qt<=ms, msub): q-slab 256 (wave = 4 A-tiles),
// m-range 128 (8 tiles, ALL preloaded).
__global__ __launch_bounds__(256) void knn_kernel(const unsigned short* __restrict__ fbA,
                                                  const unsigned short* __restrict__ fbB,
                                                  int* __restrict__ cnt,
                                                  int* __restrict__ lists) {
    int bb  = blockIdx.x & 7;
    int rem = blockIdx.x >> 3;           // 0..271 pair index
    int tri = rem >> 1, msub = rem & 1;
    int t = tri, qt = 0;
    while (t >= 16 - qt) { t -= 16 - qt; ++qt; }
    int ms = qt + t;

    int wid = threadIdx.x >> 6, lane = threadIdx.x & 63;
    int qb  = qt * 256 + wid * 64;       // wave's query base (batch-local)
    int mstart = ms * 256 + msub * 128;
    if (mstart + 128 <= qb) return;      // wave entirely below diagonal: no work

    int g16 = lane >> 4, l16 = lane & 15;
    size_t base = (size_t)bb * NN;

    // A fragments: 4 tiles of 16 q-rows (32 VGPR)
    short8 a0[4], a1[4];
#pragma unroll
    for (int a = 0; a < 4; ++a) {
        const short8* pA = (const short8*)fbA + ((base + qb + a * 16 + l16) * 8 + g16);
        a0[a] = pA[0];
        a1[a] = pA[4];   // k += 32
    }

    // B fragments: ALL 8 m-tiles preloaded (64 VGPR, 16 independent loads in flight)
    const short8* pB = (const short8*)fbB + ((base + mstart + l16) * 8 + g16);
    short8 b0[8], b1[8];
#pragma unroll
    for (int mt = 0; mt < 8; ++mt) {
        b0[mt] = pB[mt * 128];
        b1[mt] = pB[mt * 128 + 4];
    }

#pragma unroll
    for (int mt = 0; mt < 8; ++mt) {
        int mb = mstart + mt * 16;
        if (mb + 16 > qb) {              // skip tiles fully below the wave's diagonal
            int m = mb + l16;
#pragma unroll
            for (int a = 0; a < 4; ++a) {
                floatx4 acc = {0.f, 0.f, 0.f, 0.f};
                acc = __builtin_amdgcn_mfma_f32_16x16x32_bf16(a0[a], b0[mt], acc, 0, 0, 0);
                acc = __builtin_amdgcn_mfma_f32_16x16x32_bf16(a1[a], b1[mt], acc, 0, 0, 0);
                float mm = fmaxf(fmaxf(acc[0], acc[1]), fmaxf(acc[2], acc[3]));
                if (mm > 0.f) {
#pragma unroll
                    for (int r = 0; r < 4; ++r) {
                        int n = qb + a * 16 + g16 * 4 + r;   // C/D row = (lane>>4)*4 + reg
                        if (acc[r] > 0.f && m > n) {
                            int p1 = atomicAdd(&cnt[base + n], 1);
                            if (p1 < CAP) lists[(base + n) * CAP + p1] = m;
                            int p2 = atomicAdd(&cnt[base + m], 1);
                            if (p2 < CAP) lists[(base + m) * CAP + p2] = n;
                        }
                    }
                }
            }
        }
    }
}

// ---------------- phase 2: 2 queries per wave; exact fp32 weights; fused head ----------------
// XCD-pinned: bb = blockIdx & 7, j = blockIdx>>3 (0..511), block owns 8 queries.
// Lanes 0-31 = query q0 (d=hl), lanes 32-63 = q1. d=32 (noise) folded onto hl==0.
__global__ __launch_bounds__(256) void gather_kernel(const float* __restrict__ x,
                                                     const float* __restrict__ noise,
                                                     const float* __restrict__ y,
                                                     const float* __restrict__ W1,
                                                     const float* __restrict__ b1,
                                                     const int* __restrict__ cnt,
                                                     const int* __restrict__ lists,
                                                     float* __restrict__ out,
                                                     float* __restrict__ partials) {
    __shared__ float e_lds[8][2 * FF];
    __shared__ float msep[8];
    int bb = blockIdx.x & 7;
    int j  = blockIdx.x >> 3;
    int q0blk = bb * NN + j * 8;
    int wid = threadIdx.x >> 6, lane = threadIdx.x & 63;
    int hf = lane >> 5, hl = lane & 31;           // half index, lane-in-half
    int q  = q0blk + wid * 2 + hf;
    size_t base = (size_t)bb * NN;

    float fnd  = x[(size_t)q * FIN + hl];
    float fnd2 = (hl == 0) ? noise[q] : 0.f;      // d=32 slot

    int c = cnt[q];
    if (c > CAP) c = CAP;
    int mj = (hl < c) ? lists[(size_t)q * CAP + hl] : INF_IDX;

    float den = 1.f, num = 0.f, num2 = 0.f;       // self: w=1, diff=0
    for (;;) {
        int v = mj;                               // per-half min (xor<=16 stays in half)
#pragma unroll
        for (int off = 16; off; off >>= 1) {
            int o = __shfl_xor(v, off);
            v = v < o ? v : o;
        }
        if (__ballot(v != INF_IDX) == 0ull) break;   // both halves exhausted
        bool act = (v != INF_IDX);
        if (mj == v) mj = INF_IDX;
        int m = act ? v : 0;
        float fm  = x[(base + m) * (size_t)FIN + hl];
        float fm2 = (hl == 0) ? noise[base + m] : 0.f;
        float diff  = fm - fnd;
        float diff2 = fm2 - fnd2;
        float s = diff * diff + diff2 * diff2;
#pragma unroll
        for (int off = 16; off; off >>= 1) s += __shfl_xor(s, off);
        float wgt = act ? __expf(-s) : 0.f;       // exact fp32 d2
        den += wgt;
        num += wgt * diff;
        num2 += wgt * diff2;
    }
    float md = num / den, md2 = num2 / den;       // den >= 1 always

    int qs = wid * 2 + hf;                        // 0..7 query slot in block
    e_lds[qs][hl]      = fnd;
    e_lds[qs][FF + hl] = md;
    if (hl == 0) { e_lds[qs][32] = fnd2; e_lds[qs][FF + 32] = md2; }
    __syncthreads();

    // head: thread = (query hq, channel ch); 8 x 32 = 256
    int hq = threadIdx.x >> 5, ch = threadIdx.x & 31;
    int qq = q0blk + hq;
    float g0 = b1[ch], g1 = 0.f;                  // split dependent chain
#pragma unroll
    for (int e = 0; e < 2 * FF; e += 2) {
        g0 = fmaf(e_lds[hq][e],     W1[e * FIN + ch],       g0);
        g1 = fmaf(e_lds[hq][e + 1], W1[(e + 1) * FIN + ch], g1);
    }
    float g = fmaxf(g0 + g1, 0.f);
    out[(size_t)qq * FIN + ch] = g;
    float tt = g - y[(size_t)qq * FIN + ch];
    float d = tt * tt;
#pragma unroll
    for (int off = 16; off; off >>= 1) d += __shfl_xor(d, off);
    if (ch == 0) msep[hq] = d;
    __syncthreads();
    if (threadIdx.x == 0) {
        float a = 0.f;
#pragma unroll
        for (int i = 0; i < 8; ++i) a += msep[i];
        partials[blockIdx.x] = a;
    }
}

// ---------------- phase 2 (brute, ws-too-small last resort) ----------------
__global__ __launch_bounds__(256) void gather_brute(const float* __restrict__ x,
                                                    const float* __restrict__ noise,
                                                    const float* __restrict__ y,
                                                    const float* __restrict__ W1,
                                                    const float* __restrict__ b1,
                                                    float* __restrict__ out,
                                                    float* __restrict__ partials) {
    __shared__ float e_lds[4][2 * FF];
    __shared__ float msep[4];
    int wid = threadIdx.x >> 6, lane = threadIdx.x & 63;
    int q = blockIdx.x * 4 + wid;
    int bb = q >> 12;
    int nloc = q & (NN - 1);
    size_t base = (size_t)bb * NN;

    float fnd = 0.f;
    if (lane < FIN)          fnd = x[(size_t)q * FIN + lane];
    else if (lane == FF - 1) fnd = noise[q];

    float den = 1.f, num = 0.f;
    for (int m = 0; m < NN; ++m) {
        if (m == nloc) continue;
        float fmd = 0.f;
        if (lane < FIN)          fmd = x[(base + m) * (size_t)FIN + lane];
        else if (lane == FF - 1) fmd = noise[base + m];
        float diff = (lane < FF) ? (fmd - fnd) : 0.f;
        float s = diff * diff;
#pragma unroll
        for (int off = 32; off; off >>= 1) s += __shfl_xor(s, off);
        float w = __expf(-s);
        den += w;
        num += w * diff;
    }
    float md = num / den;

    if (lane < FF) { e_lds[wid][lane] = fnd; e_lds[wid][FF + lane] = md; }
    __syncthreads();
    float g = 0.f;
    if (lane < FIN) {
        g = b1[lane];
#pragma unroll
        for (int e = 0; e < 2 * FF; ++e)
            g = fmaf(e_lds[wid][e], W1[e * FIN + lane], g);
        g = fmaxf(g, 0.f);
        out[(size_t)q * FIN + lane] = g;
    }
    float d = 0.f;
    if (lane < FIN) {
        float t = g - y[(size_t)q * FIN + lane];
        d = t * t;
    }
#pragma unroll
    for (int off = 32; off; off >>= 1) d += __shfl_xor(d, off);
    if (lane == 0) msep[wid] = d;
    __syncthreads();
    if (threadIdx.x == 0)
        partials[blockIdx.x] = msep[0] + msep[1] + msep[2] + msep[3];
}

// ---------------- final: gen_mse (n4 = partial count / 4) ----------------
__global__ __launch_bounds__(256) void reduce_kernel(const float* __restrict__ partials,
                                                     float* __restrict__ out, int n4) {
    __shared__ float sw[4];
    int wid = threadIdx.x >> 6, lane = threadIdx.x & 63;
    const float4* p4 = (const float4*)partials;
    float ax = 0.f, ay = 0.f, az = 0.f, aw = 0.f;
    for (int i = threadIdx.x; i < n4; i += 256) {
        float4 v = p4[i];
        ax += v.x; ay += v.y; az += v.z; aw += v.w;
    }
    float a = (ax + ay) + (az + aw);
#pragma unroll
    for (int off = 32; off; off >>= 1) a += __shfl_xor(a, off);
    if (lane == 0) sw[wid] = a;
    __syncthreads();
    if (threadIdx.x == 0)
        out[(size_t)NQ * FIN] = (sw[0] + sw[1] + sw[2] + sw[3]) / (float)((size_t)NQ * FIN);
}

extern "C" void kernel_launch(void* const* d_in, const int* in_sizes, int n_in,
                              void* d_out, int out_size, void* d_ws, size_t ws_size,
                              hipStream_t stream) {
    const float* x     = (const float*)d_in[0];
    const float* noise = (const float*)d_in[1];
    const float* y     = (const float*)d_in[2];
    const float* W1    = (const float*)d_in[3];
    const float* b1    = (const float*)d_in[4];
    float* out = (float*)d_out;
    char* ws = (char*)d_ws;

    if (ws_size >= WS_NEED) {
        unsigned short* fbA = (unsigned short*)(ws + OFF_FBA);
        unsigned short* fbB = (unsigned short*)(ws + OFF_FBB);
        int*   cnt     = (int*)(ws + OFF_CNT);
        int*   lists   = (int*)(ws + OFF_LISTS);
        float* partial = (float*)(ws + OFF_PART);

        prep_kernel<<<NQ / 64, 64, 0, stream>>>(x, noise, fbA, fbB, cnt);
        knn_kernel<<<BB * NTRI * 2, 256, 0, stream>>>(fbA, fbB, cnt, lists);
        gather_kernel<<<NQ / 8, 256, 0, stream>>>(x, noise, y, W1, b1, cnt, lists, out, partial);
        reduce_kernel<<<1, 256, 0, stream>>>(partial, out, (NQ / 8) / 4);
    } else {
        float* partial = (float*)ws;
        gather_brute<<<NQ / 4, 256, 0, stream>>>(x, noise, y, W1, b1, out, partial);
        reduce_kernel<<<1, 256, 0, stream>>>(partial, out, (NQ / 4) / 4);
    }
}